// Round 8
// baseline (579.733 us; speedup 1.0000x reference)
//
#include <hip/hip_runtime.h>
#include <hip/hip_bf16.h>

// ---------------------------------------------------------------------------
// GraphEncoder (VGAE 2-layer GCN + reparam), fp32 in/out, edge_index int32.
// Round 16: XCD-local sliced gathers, v2 (execution fixed vs round 9).
//  * Tables stored slice-major: xsP/tsP[s][(N+1)][16 cols = 32B]; slice =
//    blockIdx&7 -> one 3.2MB slice per XCD L2 -> edge gathers L2-hit.
//  * Gather shape: 16 lanes/node, 8 edges/chunk, ONE 16B load/lane
//    (lane -> edge j=ll>>1, parity p=ll&1), cached csr idx loads with
//    1-chunk prefetch, shfl_xor(2/4/8) butterfly over j. 4 nodes/wave.
//    (Round-9 poisons fixed: no nt idx loads, no 32-node divergence.)
//  * tsP in paired {mu8|ls8} permuted-col layout (slice s = cols
//    {8s..8s+7, 64+8s..64+8s+7}) so gather2's reparam is one pair-shuffle.
//  * gemm1: dense MFMA pass ys -> tsP (round-9 proven). Build: round-14
//    bucketed CSR. Round-15 self-in-csr + splits reverted (chunk-quant
//    regression +18us).
//  * Known harness floor: ~45us x several workspace re-poison fills/iter
//    (fillBufferAligned, 307MB @6.7TB/s) — not controllable.
// Math: ts = ((Anorm@x)@Wf + 1(x)bb)*dis ; [mu|ls] = dd*(ts[d]+sum ts[s])+bcat
//       Wf = W1@[Wmu|Wls], bb = b1@[Wmu|Wls]  (rowsum-bias identity).
// ---------------------------------------------------------------------------

typedef unsigned int u32;
typedef unsigned short u16;
typedef unsigned char u8;
typedef __bf16 bf16x8 __attribute__((ext_vector_type(8)));
typedef float f32x4 __attribute__((ext_vector_type(4)));
typedef int i32x4 __attribute__((ext_vector_type(4)));
typedef u32 u32x2 __attribute__((ext_vector_type(2)));

#define NBKT 196   // ceil(100000/512)
#define BSH 9      // bucket = dst >> 9 (512 nodes/bucket)

__device__ __forceinline__ u16 f2bf(float f) {  // fp32 -> bf16 RNE
    union { float f; u32 u; } v; v.f = f;
    u32 u = v.u;
    u += 0x7fffu + ((u >> 16) & 1u);
    return (u16)(u >> 16);
}
__device__ __forceinline__ float bflo(u32 p) {
    union { u32 u; float f; } v; v.u = p << 16; return v.f;
}
__device__ __forceinline__ float bfhi(u32 p) {
    union { u32 u; float f; } v; v.u = p & 0xffff0000u; return v.f;
}

// ---------------- bcount: per-bucket edge histogram -------------------------
__global__ __launch_bounds__(256) void bcount(const int* __restrict__ dst,
                                              u32* __restrict__ bucketCnt, int E) {
    __shared__ u32 hist[NBKT];
    int t = threadIdx.x;
    for (int i = t; i < NBKT; i += 256) hist[i] = 0;
    __syncthreads();
    int base = (blockIdx.x * 256 + t) * 4;
    if (base + 3 < E) {
        i32x4 d4 = __builtin_nontemporal_load((const i32x4*)(dst + base));
        atomicAdd(&hist[d4.x >> BSH], 1u);
        atomicAdd(&hist[d4.y >> BSH], 1u);
        atomicAdd(&hist[d4.z >> BSH], 1u);
        atomicAdd(&hist[d4.w >> BSH], 1u);
    } else {
        for (int i = base; i < E; ++i) atomicAdd(&hist[dst[i] >> BSH], 1u);
    }
    __syncthreads();
    for (int i = t; i < NBKT; i += 256)
        if (hist[i]) atomicAdd(&bucketCnt[i], hist[i]);
}

// ---------------- bscan: exclusive scan of bucket counts (1 block) ----------
__global__ __launch_bounds__(256) void bscan(const u32* __restrict__ bucketCnt,
                                             u32* __restrict__ bucketStart,
                                             u32* __restrict__ bucketCur,
                                             u32* __restrict__ rowstart,
                                             int N, int E) {
    __shared__ u32 s[256];
    int t = threadIdx.x;
    u32 v = (t < NBKT) ? bucketCnt[t] : 0u;
    s[t] = v;
    for (int off = 1; off < 256; off <<= 1) {
        __syncthreads();
        u32 add = (t >= off) ? s[t - off] : 0u;
        __syncthreads();
        s[t] += add;
    }
    __syncthreads();
    if (t < NBKT) {
        u32 ex = s[t] - v;
        bucketStart[t] = ex;
        bucketCur[t] = ex;
        if (t == NBKT - 1) bucketStart[NBKT] = s[t];  // = E
    }
    if (t == 0) rowstart[N] = (u32)E;
}

// ---------------- bscatter: group edges by bucket (block-local LDS sort) ----
__global__ __launch_bounds__(256) void bscatter(const int* __restrict__ src,
                                                const int* __restrict__ dst,
                                                u32* __restrict__ bucketCur,
                                                u32* __restrict__ bksrc,
                                                u32* __restrict__ bkdst, int E) {
    __shared__ u32 hist[NBKT], lstart[NBKT], gbase[NBKT];
    __shared__ u32 sA[256];
    __shared__ u32 stS[1024], stD[1024];
    int t = threadIdx.x;
    int e0 = blockIdx.x * 1024;
    int m = min(1024, E - e0);
    for (int i = t; i < NBKT; i += 256) hist[i] = 0;
    __syncthreads();

    int sv[4], dv[4]; u32 rk[4];
    int base = e0 + t * 4;
    bool vec = (base + 3 < E);
    if (vec) {
        i32x4 s4 = __builtin_nontemporal_load((const i32x4*)(src + base));
        i32x4 d4 = __builtin_nontemporal_load((const i32x4*)(dst + base));
        sv[0] = s4.x; sv[1] = s4.y; sv[2] = s4.z; sv[3] = s4.w;
        dv[0] = d4.x; dv[1] = d4.y; dv[2] = d4.z; dv[3] = d4.w;
#pragma unroll
        for (int j = 0; j < 4; ++j) rk[j] = atomicAdd(&hist[dv[j] >> BSH], 1u);
    } else {
#pragma unroll
        for (int j = 0; j < 4; ++j) {
            if (base + j < E) {
                sv[j] = src[base + j]; dv[j] = dst[base + j];
                rk[j] = atomicAdd(&hist[dv[j] >> BSH], 1u);
            }
        }
    }
    __syncthreads();
    // exclusive scan of hist -> lstart
    sA[t] = (t < NBKT) ? hist[t] : 0u;
    for (int off = 1; off < 256; off <<= 1) {
        __syncthreads();
        u32 add = (t >= off) ? sA[t - off] : 0u;
        __syncthreads();
        sA[t] += add;
    }
    __syncthreads();
    if (t < NBKT) {
        lstart[t] = sA[t] - hist[t];
        if (hist[t]) gbase[t] = atomicAdd(&bucketCur[t], hist[t]);
    }
    __syncthreads();
    // stage sorted-by-bucket into LDS
#pragma unroll
    for (int j = 0; j < 4; ++j) {
        if (base + j < E) {
            int b = dv[j] >> BSH;
            u32 p = lstart[b] + rk[j];
            stS[p] = (u32)sv[j];
            stD[p] = (u32)dv[j];
        }
    }
    __syncthreads();
    // write out grouped (per-bucket sequential streams)
    for (int i = t; i < m; i += 256) {
        u32 d = stD[i];
        int b = (int)(d >> BSH);
        u32 g = gbase[b] + ((u32)i - lstart[b]);
        bksrc[g] = stS[i];
        bkdst[g] = d;
    }
}

// ---------------- bbuild: per-bucket deg/rowstart/dis + csr placement -------
__global__ __launch_bounds__(512) void bbuild(const u32* __restrict__ bksrc,
                                              const u32* __restrict__ bkdst,
                                              const u32* __restrict__ bucketStart,
                                              u32* __restrict__ rowstart,
                                              float* __restrict__ dis,
                                              int* __restrict__ csr, int N) {
    __shared__ u32 degL[512], exL[512];
    int t = threadIdx.x, b = blockIdx.x;
    int n0 = b << BSH;
    int nn = min(N - n0, 512);
    u32 ebeg = bucketStart[b], eend = bucketStart[b + 1];
    degL[t] = 0;
    __syncthreads();
    for (u32 e = ebeg + t; e < eend; e += 512)
        atomicAdd(&degL[bkdst[e] - (u32)n0], 1u);
    __syncthreads();
    u32 v = degL[t];
    exL[t] = v;
    for (int off = 1; off < 512; off <<= 1) {
        __syncthreads();
        u32 add = (t >= off) ? exL[t - off] : 0u;
        __syncthreads();
        exL[t] += add;
    }
    __syncthreads();
    u32 absbase = ebeg + exL[t] - v;  // absolute csr offset for local node t
    if (t < nn) {
        rowstart[n0 + t] = absbase;
        dis[n0 + t] = rsqrtf((float)v + 1.0f);
    }
    __syncthreads();
    exL[t] = absbase;  // cursor
    __syncthreads();
    for (u32 e = ebeg + t; e < eend; e += 512) {
        u32 ln = bkdst[e] - (u32)n0;
        u32 pos = atomicAdd(&exL[ln], 1u);
        csr[pos] = (int)bksrc[e];
    }
}

// ---------------- fuse weights: WfT(bf16) = (W1@[Wmu|Wls])^T, bb, bcat ------
__global__ __launch_bounds__(256) void fuse_w(const float* __restrict__ W1,
                                              const float* __restrict__ Wmu,
                                              const float* __restrict__ Wls,
                                              const float* __restrict__ b1,
                                              const float* __restrict__ bmu,
                                              const float* __restrict__ bls,
                                              u16* __restrict__ WfT,
                                              float* __restrict__ bb,
                                              float* __restrict__ bcat) {
    int idx = blockIdx.x * 256 + threadIdx.x;  // 16384
    if (idx >= 16384) return;
    int k = idx >> 7, n = idx & 127;
    const float* Wcol = (n < 64) ? (Wmu + n) : (Wls + (n - 64));
    float acc = 0.f;
#pragma unroll 8
    for (int j = 0; j < 128; ++j) acc += W1[k * 128 + j] * Wcol[j * 64];
    WfT[n * 128 + k] = f2bf(acc);  // transposed, bf16
    if (k == 0) {
        float accb = 0.f;
#pragma unroll 8
        for (int j = 0; j < 128; ++j) accb += b1[j] * Wcol[j * 64];
        bb[n] = accb;
        bcat[n] = (n < 64) ? bmu[n] : bls[n - 64];
    }
}

// ---------------- convert_x: xsP = bf16(x*dis) in slice-major layout --------
// xsP[s][(N+1)][16 cols] (32B rows). Row N zeroed in every slice (branch-free
// dummy reads; also the zero row of tsP, which aliases this buffer).
__global__ __launch_bounds__(256) void convert_x(const float* __restrict__ x,
                                                 const float* __restrict__ dis,
                                                 u32* __restrict__ xsP, int N) {
    long i = (long)blockIdx.x * 256 + threadIdx.x;  // (N+1)*32 threads
    long node = i >> 5;
    int j = (int)(i & 31);
    if (node > N) return;
    int s = j >> 2, q = j & 3;
    u32x2* dst = (u32x2*)((char*)xsP + ((size_t)s * (N + 1) + node) * 32 + q * 8);
    if (node == N) {
        u32x2 z = {0u, 0u};
        *dst = z;
        return;
    }
    float dd = dis[node];
    f32x4 v = ((const f32x4*)x)[i];
    u32x2 o;
    o.x = (u32)f2bf(v[0] * dd) | ((u32)f2bf(v[1] * dd) << 16);
    o.y = (u32)f2bf(v[2] * dd) | ((u32)f2bf(v[3] * dd) << 16);
    *dst = o;
}

// ---------------- gather1s: ys[s][node] = bf16(dd*(xs[n] + sum xs[src])) ----
// slice = bid&7 (XCD-pinned). 16 subgroups of 16 lanes; subgroup = 1 node;
// lane = (edge j=ll>>1, parity p=ll&1): one 16B load per lane per 8-edge
// chunk; butterfly shfl_xor(2/4/8) sums over j.
__global__ __launch_bounds__(256) void gather1s(const u32* __restrict__ xsP,
                                                const int* __restrict__ csr,
                                                const u32* __restrict__ rowstart,
                                                const float* __restrict__ dis,
                                                u32* __restrict__ ys, int N) {
    int tid = threadIdx.x;
    u32 bid = blockIdx.x;
    int s = bid & 7;
    int sg = tid >> 4, ll = tid & 15;
    int j = ll >> 1, p = ll & 1;
    int node = (int)(bid >> 3) * 16 + sg;
    bool live = node < N;
    int nodeC = live ? node : 0;
    float dd = dis[nodeC];
    u32 beg = rowstart[nodeC];
    u32 end = live ? rowstart[nodeC + 1] : beg;
    const uint4* base = (const uint4*)(xsP + (size_t)s * (N + 1) * 8);

    float a0 = 0.f, a1 = 0.f, a2 = 0.f, a3 = 0.f;
    float a4 = 0.f, a5 = 0.f, a6 = 0.f, a7 = 0.f;

    u32 e0 = beg + (u32)j;
    int idx = (e0 < end) ? csr[e0] : N;
    for (u32 c = beg; c < end; c += 8) {
        u32 c1 = c + 8;
        int idxn = (c1 + (u32)j < end) ? csr[c1 + (u32)j] : N;
        uint4 v = base[(size_t)idx * 2 + p];
        a0 += bflo(v.x); a1 += bfhi(v.x);
        a2 += bflo(v.y); a3 += bfhi(v.y);
        a4 += bflo(v.z); a5 += bfhi(v.z);
        a6 += bflo(v.w); a7 += bfhi(v.w);
        idx = idxn;
    }
    // butterfly over j (lane bits 1..3)
#pragma unroll
    for (int m = 2; m <= 8; m <<= 1) {
        a0 += __shfl_xor(a0, m); a1 += __shfl_xor(a1, m);
        a2 += __shfl_xor(a2, m); a3 += __shfl_xor(a3, m);
        a4 += __shfl_xor(a4, m); a5 += __shfl_xor(a5, m);
        a6 += __shfl_xor(a6, m); a7 += __shfl_xor(a7, m);
    }
    if (j != 0) return;  // lanes 0,1 of each subgroup hold full sums
    // self row (L2-resident: it is the slice)
    uint4 sv = base[(size_t)nodeC * 2 + p];
    a0 += bflo(sv.x); a1 += bfhi(sv.x);
    a2 += bflo(sv.y); a3 += bfhi(sv.y);
    a4 += bflo(sv.z); a5 += bfhi(sv.z);
    a6 += bflo(sv.w); a7 += bfhi(sv.w);
    if (!live) return;
    uint4 o;
    o.x = (u32)f2bf(a0 * dd) | ((u32)f2bf(a1 * dd) << 16);
    o.y = (u32)f2bf(a2 * dd) | ((u32)f2bf(a3 * dd) << 16);
    o.z = (u32)f2bf(a4 * dd) | ((u32)f2bf(a5 * dd) << 16);
    o.w = (u32)f2bf(a6 * dd) | ((u32)f2bf(a7 * dd) << 16);
    ((uint4*)ys)[((size_t)s * (N + 1) + node) * 2 + p] = o;
}

// ---------------- gemm1: tsP = bf16((ys@Wf + bb)*dis), paired slices --------
// tsP slice s holds cols {8s..8s+7}(mu) and {64+8s..}(ls): [s][(N+1)][16].
// Row N stays zero (aliases xsP zero row; only rows<N written).
__global__ __launch_bounds__(256) void gemm1(const u32* __restrict__ ys,
                                             const u16* __restrict__ WfT,
                                             const float* __restrict__ bb,
                                             const float* __restrict__ dis,
                                             u16* __restrict__ tsP, int N) {
    __shared__ __align__(16) u16 ytile[16][136];
    __shared__ float disS[16];
    int tid = threadIdx.x, blk = blockIdx.x;
    int node0 = blk * 16;
    if (tid < 16) disS[tid] = (node0 + tid < N) ? dis[node0 + tid] : 0.f;
    int row = tid >> 4, ch = tid & 15;
    int gn = node0 + row;
    int gnC = (gn < N) ? gn : (N - 1);
    // ys slice-major: cols [8ch..8ch+7] = slice ch>>1, parity ch&1
    uint4 av = ((const uint4*)ys)[((size_t)(ch >> 1) * (N + 1) + gnC) * 2 + (ch & 1)];
    *(uint4*)&ytile[row][ch * 8] = av;
    __syncthreads();

    int wave = tid >> 6, lane = tid & 63, quad = lane >> 4, mn = lane & 15;
    bf16x8 af[4];
#pragma unroll
    for (int kk = 0; kk < 4; ++kk)
        af[kk] = *reinterpret_cast<const bf16x8*>(&ytile[mn][kk * 32 + quad * 8]);

#pragma unroll
    for (int n0 = 0; n0 < 2; ++n0) {
        int col = wave * 32 + n0 * 16 + mn;
        f32x4 acc = {0.f, 0.f, 0.f, 0.f};
#pragma unroll
        for (int kk = 0; kk < 4; ++kk) {
            bf16x8 bf =
                *reinterpret_cast<const bf16x8*>(&WfT[col * 128 + kk * 32 + quad * 8]);
            acc = __builtin_amdgcn_mfma_f32_16x16x32_bf16(af[kk], bf, acc, 0, 0, 0);
        }
        float bc = bb[col];
        int sC = (col < 64) ? (col >> 3) : ((col - 64) >> 3);
        int posC = (col & 7) + ((col < 64) ? 0 : 8);
        u16* op = tsP + ((size_t)sC * (N + 1) + node0) * 16 + posC;
#pragma unroll
        for (int r = 0; r < 4; ++r) {  // C/D: col=lane&15(+16*n0), row=quad*4+r
            int rr = quad * 4 + r;
            if (node0 + rr < N)
                __builtin_nontemporal_store(f2bf((acc[r] + bc) * disS[rr]),
                                            op + (size_t)rr * 16);
        }
    }
}

// ---------------- gather2s: out = dd*(ts[d]+sum ts[src]) + bcat + reparam ---
// Same sliced skeleton. After butterfly: lane p=0 holds mu cols 8s..8s+7,
// p=1 holds ls cols; z = mu + eps*exp(ls) via one pair shuffle.
__global__ __launch_bounds__(256) void gather2s(const u32* __restrict__ tsP,
                                                const int* __restrict__ csr,
                                                const u32* __restrict__ rowstart,
                                                const float* __restrict__ dis,
                                                const float* __restrict__ bcat,
                                                const float* __restrict__ eps,
                                                float* __restrict__ out, int N) {
    int tid = threadIdx.x;
    u32 bid = blockIdx.x;
    int s = bid & 7;
    int sg = tid >> 4, ll = tid & 15;
    int j = ll >> 1, p = ll & 1;
    int node = (int)(bid >> 3) * 16 + sg;
    bool live = node < N;
    int nodeC = live ? node : 0;
    float dd = dis[nodeC];
    u32 beg = rowstart[nodeC];
    u32 end = live ? rowstart[nodeC + 1] : beg;
    const uint4* base = (const uint4*)(tsP + (size_t)s * (N + 1) * 8);

    float a0 = 0.f, a1 = 0.f, a2 = 0.f, a3 = 0.f;
    float a4 = 0.f, a5 = 0.f, a6 = 0.f, a7 = 0.f;

    u32 e0 = beg + (u32)j;
    int idx = (e0 < end) ? csr[e0] : N;
    for (u32 c = beg; c < end; c += 8) {
        u32 c1 = c + 8;
        int idxn = (c1 + (u32)j < end) ? csr[c1 + (u32)j] : N;
        uint4 v = base[(size_t)idx * 2 + p];
        a0 += bflo(v.x); a1 += bfhi(v.x);
        a2 += bflo(v.y); a3 += bfhi(v.y);
        a4 += bflo(v.z); a5 += bfhi(v.z);
        a6 += bflo(v.w); a7 += bfhi(v.w);
        idx = idxn;
    }
#pragma unroll
    for (int m = 2; m <= 8; m <<= 1) {
        a0 += __shfl_xor(a0, m); a1 += __shfl_xor(a1, m);
        a2 += __shfl_xor(a2, m); a3 += __shfl_xor(a3, m);
        a4 += __shfl_xor(a4, m); a5 += __shfl_xor(a5, m);
        a6 += __shfl_xor(a6, m); a7 += __shfl_xor(a7, m);
    }
    if (j != 0) return;  // lanes 0 (mu) and 1 (ls) of each subgroup continue
    uint4 sv = base[(size_t)nodeC * 2 + p];
    a0 += bflo(sv.x); a1 += bfhi(sv.x);
    a2 += bflo(sv.y); a3 += bfhi(sv.y);
    a4 += bflo(sv.z); a5 += bfhi(sv.z);
    a6 += bflo(sv.w); a7 += bfhi(sv.w);

    const f32x4* bc = (const f32x4*)(bcat + (p ? 64 + 8 * s : 8 * s));
    f32x4 c0 = bc[0], c1 = bc[1];
    float v0 = a0 * dd + c0[0], v1 = a1 * dd + c0[1];
    float v2 = a2 * dd + c0[2], v3 = a3 * dd + c0[3];
    float v4 = a4 * dd + c1[0], v5 = a5 * dd + c1[1];
    float v6 = a6 * dd + c1[2], v7 = a7 * dd + c1[3];

    // ls values live on the pair partner (lane^1); both lanes active here.
    float w0 = __shfl_xor(v0, 1), w1 = __shfl_xor(v1, 1), w2 = __shfl_xor(v2, 1),
          w3 = __shfl_xor(v3, 1), w4 = __shfl_xor(v4, 1), w5 = __shfl_xor(v5, 1),
          w6 = __shfl_xor(v6, 1), w7 = __shfl_xor(v7, 1);

    if (!live) return;
    long NO = (long)N * 64;
    if (p == 0) {  // mu cols 8s..8s+7 ; also compute z
        float* mu = out + NO + (long)node * 64 + 8 * s;
        __builtin_nontemporal_store(f32x4{v0, v1, v2, v3}, (f32x4*)mu);
        __builtin_nontemporal_store(f32x4{v4, v5, v6, v7}, (f32x4*)mu + 1);
        const f32x4* ep = (const f32x4*)(eps + (long)node * 64 + 8 * s);
        f32x4 e0v = __builtin_nontemporal_load(ep);
        f32x4 e1v = __builtin_nontemporal_load(ep + 1);
        float* z = out + (long)node * 64 + 8 * s;
        f32x4 z0 = {v0 + e0v[0] * __expf(w0), v1 + e0v[1] * __expf(w1),
                    v2 + e0v[2] * __expf(w2), v3 + e0v[3] * __expf(w3)};
        f32x4 z1 = {v4 + e1v[0] * __expf(w4), v5 + e1v[1] * __expf(w5),
                    v6 + e1v[2] * __expf(w6), v7 + e1v[3] * __expf(w7)};
        __builtin_nontemporal_store(z0, (f32x4*)z);
        __builtin_nontemporal_store(z1, (f32x4*)z + 1);
    } else {       // logstd cols 8s..8s+7 of ls block
        float* ls = out + 2 * NO + (long)node * 64 + 8 * s;
        __builtin_nontemporal_store(f32x4{v0, v1, v2, v3}, (f32x4*)ls);
        __builtin_nontemporal_store(f32x4{v4, v5, v6, v7}, (f32x4*)ls + 1);
    }
}

// ---------------------------------------------------------------------------
extern "C" void kernel_launch(void* const* d_in, const int* in_sizes, int n_in,
                              void* d_out, int out_size, void* d_ws, size_t ws_size,
                              hipStream_t stream) {
    const float* x   = (const float*)d_in[0];
    const int* ei    = (const int*)d_in[1];
    const float* W1  = (const float*)d_in[2];
    const float* b1  = (const float*)d_in[3];
    const float* Wmu = (const float*)d_in[4];
    const float* bmu = (const float*)d_in[5];
    const float* Wls = (const float*)d_in[6];
    const float* bls = (const float*)d_in[7];
    const float* eps = (const float*)d_in[8];
    float* out = (float*)d_out;

    const int N = in_sizes[0] / 128;   // 100000
    const int E = in_sizes[1] / 2;     // 1600000
    const int* src = ei;
    const int* dst = ei + E;

    // WS layout (bytes), ~58.4 MB.
    char* ws = (char*)d_ws;
    u32* rowstart    = (u32*)(ws + 0);          //   400,004
    u32* bucketCnt   = (u32*)(ws + 401408);     //     1,024
    u32* bucketStart = (u32*)(ws + 403456);     //     1,024
    u32* bucketCur   = (u32*)(ws + 405504);     //     1,024
    float* dis       = (float*)(ws + 407552);   //   400,000
    u16* WfT         = (u16*)(ws + 808960);     //    32,768
    float* bb        = (float*)(ws + 841728);   //       512
    float* bcat      = (float*)(ws + 842240);   //       512
    int* csr         = (int*)(ws + 843776);     // 6,400,000 (E entries)
    u32* xsP         = (u32*)(ws + 7244800);    // 25,600,256 (8 x (N+1) x 32B)
    u32* ys          = (u32*)(ws + 32845056);   // 25,600,256 (8 x (N+1) x 32B)
    u16* tsP         = (u16*)xsP;               // alias: xsP dead after gather1s;
                                                // zero row N survives for gather2s.
    // bk scratch aliases xsP region (dead before convert_x writes xsP).
    u32* bksrc       = (u32*)(ws + 7244800);    // 6,400,000
    u32* bkdst       = (u32*)(ws + 13644800);   // 6,400,000

    hipMemsetAsync(bucketCnt, 0, 1024, stream);

    int gridE4 = (E / 4 + 255) / 256;  // 1563 blocks, 1024 edges each
    bcount<<<gridE4, 256, 0, stream>>>(dst, bucketCnt, E);
    bscan<<<1, 256, 0, stream>>>(bucketCnt, bucketStart, bucketCur, rowstart, N, E);
    bscatter<<<gridE4, 256, 0, stream>>>(src, dst, bucketCur, bksrc, bkdst, E);
    bbuild<<<NBKT, 512, 0, stream>>>(bksrc, bkdst, bucketStart, rowstart, dis,
                                     csr, N);

    fuse_w<<<64, 256, 0, stream>>>(W1, Wmu, Wls, b1, bmu, bls, WfT, bb, bcat);

    long Qc = (long)(N + 1) * 32;  // 8B-granular threads incl. zero rows
    convert_x<<<(int)((Qc + 255) / 256), 256, 0, stream>>>(x, dis, xsP, N);

    int gridS = 8 * ((N + 15) / 16);  // slice = blockIdx & 7, 16 nodes/block
    gather1s<<<gridS, 256, 0, stream>>>(xsP, csr, rowstart, dis, ys, N);

    gemm1<<<(N + 15) / 16, 256, 0, stream>>>(ys, WfT, bb, dis, tsP, N);

    gather2s<<<gridS, 256, 0, stream>>>((const u32*)tsP, csr, rowstart, dis,
                                        bcat, eps, out, N);
}